// Round 7
// baseline (228.235 us; speedup 1.0000x reference)
//
#include <hip/hip_runtime.h>
#include <math.h>

#define NCLS 80
#define BINS 16
#define BATCH 32
#define MAX_GT 32
#define NA 8400
#define AN (BATCH * NA)        // 268800 anchors
#define NT 2100                // anchor-quads per image
#define NQG (BATCH * NT)       // 67200 quad-groups total
#define NB_DFL 263             // ceil(67200/256) blocks of 1024 (256 quads x 4 sides)
#define NB_CLS 5120            // 2 blocks per (b,c) plane
#define NSLOT 64
#define ALPHA_C 0.25f
#define W_CLS 1.0
#define W_IOU 7.5
#define W_DFL 1.5
#define EPS_F 1e-7f

// acc: 4 quantities x 64 slots (double): [0]=cls [1]=iou [2]=dfl [3]=pos_count

// block = 1024 threads (16 waves). One atomic per call.
__device__ __forceinline__ void block_reduce_atomic_16(float val, double* __restrict__ target)
{
    __shared__ float s[16];
    __syncthreads();
    #pragma unroll
    for (int o = 32; o > 0; o >>= 1) val += __shfl_down(val, o);
    const int wave = threadIdx.x >> 6, lane = threadIdx.x & 63;
    if (lane == 0) s[wave] = val;
    __syncthreads();
    if (threadIdx.x == 0) {
        float t = 0.f;
        #pragma unroll
        for (int i = 0; i < 16; ++i) t += s[i];
        atomicAdd(target, (double)t);
    }
}

__device__ __forceinline__ void block_reduce_atomic_4(float val, double* __restrict__ target)
{
    __shared__ float s[4];
    __syncthreads();
    #pragma unroll
    for (int o = 32; o > 0; o >>= 1) val += __shfl_down(val, o);
    const int wave = threadIdx.x >> 6, lane = threadIdx.x & 63;
    if (lane == 0) s[wave] = val;
    __syncthreads();
    if (threadIdx.x == 0) atomicAdd(target, (double)(s[0] + s[1] + s[2] + s[3]));
}

__device__ __forceinline__ float focal_elem(float s, float tt)
{
    float e   = __expf(-fabsf(s));
    float inv = 1.f / (1.f + e);
    float prob = (s >= 0.f) ? inv : e * inv;           // sigmoid(s)
    float ce  = fmaxf(s, 0.f) - s * tt + __logf(1.f + e);
    float p_t = prob * tt + (1.f - prob) * (1.f - tt);
    float alpha_t = tt * ALPHA_C + (1.f - tt) * (1.f - ALPHA_C);
    float om = 1.f - p_t;
    return alpha_t * om * om * ce;
}

// quad t (0..2099) -> scale geometry
__device__ __forceinline__ void quad_map(int t, int& HW, int& off, int& gbase,
                                         int& h, int& w0, float& stride)
{
    if (t < 1600)      { HW = 6400; off = t * 4;          gbase = 0;    stride = 8.f;
                         h = t / 20;  w0 = (t - h * 20) * 4; }
    else if (t < 2000) { HW = 1600; off = (t - 1600) * 4; gbase = 6400; stride = 16.f;
                         int u = t - 1600; h = u / 10; w0 = (u - h * 10) * 4; }
    else               { HW = 400;  off = (t - 2000) * 4; gbase = 8000; stride = 32.f;
                         int u = t - 2000; h = u / 5;  w0 = (u - h * 5) * 4; }
}

// ---------------- prep: per-anchor int8 label table (-1 = negative) + zero acc ----------------
__global__ __launch_bounds__(256) void yolo_prep(
    const int* __restrict__ matched, const int* __restrict__ gt_labels,
    signed char* __restrict__ lblmap, double* __restrict__ acc)
{
    if (blockIdx.x == 0) acc[threadIdx.x] = 0.0;       // 256 = 4*NSLOT doubles
    const int qid = blockIdx.x * 256 + threadIdx.x;
    if (qid >= AN / 4) return;
    const int a0 = qid * 4;
    const int b  = a0 / NA;
    const int4 m4 = *(const int4*)(matched + a0);
    const int mm[4] = {m4.x, m4.y, m4.z, m4.w};
    char4 o;
    o.x = (mm[0] >= 0) ? (signed char)gt_labels[b * MAX_GT + mm[0]] : (signed char)-1;
    o.y = (mm[1] >= 0) ? (signed char)gt_labels[b * MAX_GT + mm[1]] : (signed char)-1;
    o.z = (mm[2] >= 0) ? (signed char)gt_labels[b * MAX_GT + mm[2]] : (signed char)-1;
    o.w = (mm[3] >= 0) ? (signed char)gt_labels[b * MAX_GT + mm[3]] : (signed char)-1;
    *(char4*)(lblmap + a0) = o;
}

// ---------------- mega: 1024-thread blocks; DFL+IoU blocks first, then cls ----------------
__global__ __launch_bounds__(1024, 8) void yolo_mega(
    const float* __restrict__ p0, const float* __restrict__ p1, const float* __restrict__ p2,
    const float* __restrict__ gt_bboxes, const int* __restrict__ matched,
    const signed char* __restrict__ lblmap, double* __restrict__ acc)
{
    const int bid  = blockIdx.x;
    const int slot = bid & (NSLOT - 1);

    if (bid < NB_DFL) {
        // ---- DFL + IoU: thread = (quad-group, side k); k in HIGH bits -> contiguous row loads
        __shared__ float4 spd[4][256];                 // [k][local quad] -> pd for 4 anchors
        const int local = threadIdx.x & 255;
        const int k     = threadIdx.x >> 8;            // wave-uniform
        const int qg    = bid * 256 + local;
        const bool valid = (qg < NQG);
        const int qv = valid ? qg : 0;
        const int b  = qv / NT;
        const int t  = qv - b * NT;

        int HW, off, gbase, h, w0; float stride;
        quad_map(t, HW, off, gbase, h, w0, stride);
        const float inv_s = 1.f / stride;
        const float cy = ((float)h + 0.5f) * stride;
        const float* p = (t < 1600) ? p0 : (t < 2000) ? p1 : p2;

        // matched + target distance for this side only (tbv not kept live)
        const int4 m4 = *(const int4*)(matched + (size_t)b * NA + gbase + off);
        const int mm[4] = {m4.x, m4.y, m4.z, m4.w};
        int lo[4]; float fr[4]; bool pos[4];
        #pragma unroll
        for (int j = 0; j < 4; ++j) {
            pos[j] = (mm[j] >= 0);
            int idx = pos[j] ? mm[j] : 0;
            float4 tb = *(const float4*)(gt_bboxes + ((size_t)b * MAX_GT + idx) * 4);
            float cx = ((float)(w0 + j) + 0.5f) * stride;
            float d = (k == 0) ? (cx - tb.x) : (k == 1) ? (cy - tb.y)
                    : (k == 2) ? (tb.z - cx) : (tb.w - cy);
            float tval = fminf(fmaxf(d, 0.f) * inv_s, (float)(BINS - 1) - 1e-6f);
            lo[j] = (int)floorf(tval);                 // 0..14
            fr[j] = tval - (float)lo[j];
        }

        // online softmax over 16 bin-rows (no v[16] storage)
        const float* pc = p + (size_t)(b * 144 + k * BINS) * HW + off;
        float mx[4], se[4], we[4], vlo[4], vhi[4];
        #pragma unroll
        for (int j = 0; j < 4; ++j) { mx[j] = -1e30f; se[j] = 0.f; we[j] = 0.f; vlo[j] = 0.f; vhi[j] = 0.f; }

        #pragma unroll 4
        for (int i = 0; i < BINS; ++i) {
            float4 q = {0.f, 0.f, 0.f, 0.f};
            if (valid) q = *(const float4*)(pc + (size_t)i * HW);
            const float vj[4] = {q.x, q.y, q.z, q.w};
            #pragma unroll
            for (int j = 0; j < 4; ++j) {
                float v = vj[j];
                float nm = fmaxf(mx[j], v);
                float scale = __expf(mx[j] - nm);      // 1 when max unchanged
                float e = __expf(v - nm);
                se[j] = se[j] * scale + e;
                we[j] = we[j] * scale + (float)i * e;
                mx[j] = nm;
                vlo[j] = (i == lo[j])     ? v : vlo[j];
                vhi[j] = (i == lo[j] + 1) ? v : vhi[j];
            }
        }

        float part = 0.f;
        float pd[4];
        #pragma unroll
        for (int j = 0; j < 4; ++j) {
            pd[j] = (we[j] / se[j]) * stride;
            if (valid && pos[j]) {
                float lse = mx[j] + __logf(se[j]);
                part += -((1.f - fr[j]) * (vlo[j] - lse) + fr[j] * (vhi[j] - lse));
            }
        }
        spd[k][local] = make_float4(pd[0], pd[1], pd[2], pd[3]);
        __syncthreads();

        float iou_part = 0.f, cnt = 0.f;
        if (k == 0 && valid) {
            const float4 q0 = spd[0][local], q1 = spd[1][local];
            const float4 q2 = spd[2][local], q3 = spd[3][local];
            const float l_[4] = {q0.x, q0.y, q0.z, q0.w};
            const float t_[4] = {q1.x, q1.y, q1.z, q1.w};
            const float r_[4] = {q2.x, q2.y, q2.z, q2.w};
            const float b_[4] = {q3.x, q3.y, q3.z, q3.w};
            #pragma unroll
            for (int j = 0; j < 4; ++j) {
                if (pos[j]) {
                    float4 tb = *(const float4*)(gt_bboxes + ((size_t)b * MAX_GT + mm[j]) * 4);
                    float cx = ((float)(w0 + j) + 0.5f) * stride;
                    float px1 = cx - l_[j], py1 = cy - t_[j];
                    float px2 = cx + r_[j], py2 = cy + b_[j];
                    float ix1 = fmaxf(px1, tb.x), iy1 = fmaxf(py1, tb.y);
                    float ix2 = fminf(px2, tb.z), iy2 = fminf(py2, tb.w);
                    float inter  = fmaxf(ix2 - ix1, 0.f) * fmaxf(iy2 - iy1, 0.f);
                    float area_p = fmaxf(px2 - px1, 0.f) * fmaxf(py2 - py1, 0.f);
                    float area_t = fmaxf(tb.z - tb.x, 0.f) * fmaxf(tb.w - tb.y, 0.f);
                    float iou = inter / (area_p + area_t - inter + EPS_F);
                    iou_part += 1.f - iou;
                    cnt += 1.f;
                }
            }
        }
        block_reduce_atomic_16(part,     &acc[2 * NSLOT + slot]);
        block_reduce_atomic_16(iou_part, &acc[1 * NSLOT + slot]);
        block_reduce_atomic_16(cnt,      &acc[3 * NSLOT + slot]);
    } else {
        // ---- cls: 2 blocks per (b,c) plane; thread = one quad (4 anchors) ----
        const int cbid  = bid - NB_DFL;                // 0..5119
        const int half  = cbid & 1;
        const int plane = cbid >> 1;
        const int b = plane / NCLS;
        const int c = plane - b * NCLS;
        const size_t cls_ch = (size_t)(b * 144 + 4 * BINS + c);
        const signed char* lb0 = lblmap + b * NA;

        float part = 0.f;
        for (int q = (int)threadIdx.x; q < 1050; q += 1024) {
            const int t = half * 1050 + q;             // quad in image
            const float* p; int HW, off, gbase;
            if (t < 1600)      { p = p0; HW = 6400; off = t * 4;          gbase = 0;    }
            else if (t < 2000) { p = p1; HW = 1600; off = (t - 1600) * 4; gbase = 6400; }
            else               { p = p2; HW = 400;  off = (t - 2000) * 4; gbase = 8000; }

            float4 s4 = *(const float4*)(p + cls_ch * HW + off);
            char4  l4 = *(const char4*)(lb0 + gbase + off);
            part += focal_elem(s4.x, (c == l4.x) ? 1.f : 0.f);
            part += focal_elem(s4.y, (c == l4.y) ? 1.f : 0.f);
            part += focal_elem(s4.z, (c == l4.z) ? 1.f : 0.f);
            part += focal_elem(s4.w, (c == l4.w) ? 1.f : 0.f);
        }
        block_reduce_atomic_16(part, &acc[0 * NSLOT + slot]);
    }
}

// ---------------- fallback: known-good fused kernel (round 1) ----------------
__global__ __launch_bounds__(256) void yolo_loss_fused(
    const float* __restrict__ p0, const float* __restrict__ p1, const float* __restrict__ p2,
    const float* __restrict__ gt_bboxes, const int* __restrict__ gt_labels,
    const int* __restrict__ matched, double* __restrict__ acc)
{
    const int a = blockIdx.x * blockDim.x + threadIdx.x;
    const int b = blockIdx.y;
    const int slot = blockIdx.x & (NSLOT - 1);
    float cls_acc = 0.f, iou_acc = 0.f, dfl_acc = 0.f, pos_cnt = 0.f;
    if (a < NA) {
        const float* p; int HW, W; float stride; int off;
        if (a < 6400)      { p = p0; HW = 6400; W = 80; stride = 8.f;  off = a; }
        else if (a < 8000) { p = p1; HW = 1600; W = 40; stride = 16.f; off = a - 6400; }
        else               { p = p2; HW = 400;  W = 20; stride = 32.f; off = a - 8000; }
        const int h = off / W, w = off - h * W;
        const float cx = ((float)w + 0.5f) * stride, cy = ((float)h + 0.5f) * stride;
        const float* pb = p + ((size_t)b * 144) * (size_t)HW + (size_t)off;
        const int m = matched[(size_t)b * NA + a];
        const bool pos = (m >= 0);
        const int idx = pos ? m : 0;
        const int lbl = gt_labels[b * MAX_GT + idx];
        const float* tbp = gt_bboxes + ((size_t)b * MAX_GT + idx) * 4;
        const float tx1 = tbp[0], ty1 = tbp[1], tx2 = tbp[2], ty2 = tbp[3];
        float tdist[4] = {fmaxf(cx - tx1, 0.f) / stride, fmaxf(cy - ty1, 0.f) / stride,
                          fmaxf(tx2 - cx, 0.f) / stride, fmaxf(ty2 - cy, 0.f) / stride};
        float pdv[4]; float dfl_sum = 0.f;
        #pragma unroll
        for (int k = 0; k < 4; ++k) {
            float tv = fminf(tdist[k], (float)(BINS - 1) - 1e-6f);
            int lo = (int)floorf(tv);
            float fr = tv - (float)lo;
            const float* pc = pb + (size_t)(k * BINS) * HW;
            float v[BINS];
            #pragma unroll
            for (int i = 0; i < BINS; ++i) v[i] = pc[(size_t)i * HW];
            float mx = v[0];
            #pragma unroll
            for (int i = 1; i < BINS; ++i) mx = fmaxf(mx, v[i]);
            float se = 0.f, we = 0.f, vlo = 0.f, vhi = 0.f;
            #pragma unroll
            for (int i = 0; i < BINS; ++i) {
                float e = __expf(v[i] - mx);
                se += e; we += (float)i * e;
                vlo = (i == lo) ? v[i] : vlo;
                vhi = (i == lo + 1) ? v[i] : vhi;
            }
            pdv[k] = (we / se) * stride;
            if (pos) { float lse = mx + __logf(se); dfl_sum += -((1.f - fr) * (vlo - lse) + fr * (vhi - lse)); }
        }
        const float* pcls = pb + (size_t)(4 * BINS) * HW;
        #pragma unroll 4
        for (int c = 0; c < NCLS; ++c)
            cls_acc += focal_elem(pcls[(size_t)c * HW], (pos && c == lbl) ? 1.f : 0.f);
        if (pos) {
            float px1 = cx - pdv[0], py1 = cy - pdv[1], px2 = cx + pdv[2], py2 = cy + pdv[3];
            float ix1 = fmaxf(px1, tx1), iy1 = fmaxf(py1, ty1);
            float ix2 = fminf(px2, tx2), iy2 = fminf(py2, ty2);
            float inter  = fmaxf(ix2 - ix1, 0.f) * fmaxf(iy2 - iy1, 0.f);
            float area_p = fmaxf(px2 - px1, 0.f) * fmaxf(py2 - py1, 0.f);
            float area_t = fmaxf(tx2 - tx1, 0.f) * fmaxf(ty2 - ty1, 0.f);
            float iou = inter / (area_p + area_t - inter + EPS_F);
            iou_acc = 1.f - iou; dfl_acc = dfl_sum; pos_cnt = 1.f;
        }
    }
    block_reduce_atomic_4(cls_acc, &acc[0 * NSLOT + slot]);
    block_reduce_atomic_4(iou_acc, &acc[1 * NSLOT + slot]);
    block_reduce_atomic_4(dfl_acc, &acc[2 * NSLOT + slot]);
    block_reduce_atomic_4(pos_cnt, &acc[3 * NSLOT + slot]);
}

__global__ void yolo_loss_finalize(const double* __restrict__ acc, float* __restrict__ out)
{
    double s[4] = {0.0, 0.0, 0.0, 0.0};
    for (int q = 0; q < 4; ++q)
        for (int i = 0; i < NSLOT; ++i) s[q] += acc[q * NSLOT + i];
    double np = s[3] < 1.0 ? 1.0 : s[3];
    double total = W_CLS * s[0] / np + W_IOU * s[1] / np + W_DFL * s[2] / (np * 4.0);
    out[0] = (float)total;
}

extern "C" void kernel_launch(void* const* d_in, const int* in_sizes, int n_in,
                              void* d_out, int out_size, void* d_ws, size_t ws_size,
                              hipStream_t stream)
{
    const float* p0        = (const float*)d_in[0];
    const float* p1        = (const float*)d_in[1];
    const float* p2        = (const float*)d_in[2];
    const float* gt_bboxes = (const float*)d_in[3];
    const int*   gt_labels = (const int*)d_in[4];
    const int*   matched   = (const int*)d_in[5];
    float*  out = (float*)d_out;

    const size_t accBytes = 4 * NSLOT * sizeof(double);                 // 2048
    double*      acc    = (double*)d_ws;
    signed char* lblmap = (signed char*)((char*)d_ws + accBytes);
    const size_t need = accBytes + (size_t)AN;                          // ~271 KB

    if (ws_size >= need) {
        yolo_prep<<<(AN / 4 + 255) / 256, 256, 0, stream>>>(matched, gt_labels, lblmap, acc);
        yolo_mega<<<NB_DFL + NB_CLS, 1024, 0, stream>>>(p0, p1, p2, gt_bboxes, matched,
                                                        lblmap, acc);
    } else {
        (void)hipMemsetAsync(acc, 0, accBytes, stream);
        dim3 g((NA + 255) / 256, BATCH);
        yolo_loss_fused<<<g, 256, 0, stream>>>(p0, p1, p2, gt_bboxes, gt_labels, matched, acc);
    }
    yolo_loss_finalize<<<1, 1, 0, stream>>>(acc, out);
}

// Round 8
// 217.571 us; speedup vs baseline: 1.0490x; 1.0490x over previous
//
#include <hip/hip_runtime.h>
#include <math.h>

#define NCLS 80
#define BINS 16
#define BATCH 32
#define MAX_GT 32
#define NA 8400
#define AN (BATCH * NA)        // 268800 anchors
#define NT 2100                // anchor-quads per image
#define NB_DFL 1050            // 1050*1024 = 268800 anchors x 4 sides
#define NB_CLS 5120            // 2 blocks per (b,c) plane
#define NSLOT 64
#define ALPHA_C 0.25f
#define W_CLS 1.0
#define W_IOU 7.5
#define W_DFL 1.5
#define EPS_F 1e-7f

// acc: 4 quantities x 64 slots (double): [0]=cls [1]=iou [2]=dfl [3]=pos_count

// block = 1024 threads (16 waves). One atomic per call.
__device__ __forceinline__ void block_reduce_atomic_16(float val, double* __restrict__ target)
{
    __shared__ float s[16];
    __syncthreads();
    #pragma unroll
    for (int o = 32; o > 0; o >>= 1) val += __shfl_down(val, o);
    const int wave = threadIdx.x >> 6, lane = threadIdx.x & 63;
    if (lane == 0) s[wave] = val;
    __syncthreads();
    if (threadIdx.x == 0) {
        float t = 0.f;
        #pragma unroll
        for (int i = 0; i < 16; ++i) t += s[i];
        atomicAdd(target, (double)t);
    }
}

__device__ __forceinline__ void block_reduce_atomic_4(float val, double* __restrict__ target)
{
    __shared__ float s[4];
    __syncthreads();
    #pragma unroll
    for (int o = 32; o > 0; o >>= 1) val += __shfl_down(val, o);
    const int wave = threadIdx.x >> 6, lane = threadIdx.x & 63;
    if (lane == 0) s[wave] = val;
    __syncthreads();
    if (threadIdx.x == 0) atomicAdd(target, (double)(s[0] + s[1] + s[2] + s[3]));
}

__device__ __forceinline__ float focal_elem(float s, float tt)
{
    float e   = __expf(-fabsf(s));
    float inv = 1.f / (1.f + e);
    float prob = (s >= 0.f) ? inv : e * inv;           // sigmoid(s)
    float ce  = fmaxf(s, 0.f) - s * tt + __logf(1.f + e);
    float p_t = prob * tt + (1.f - prob) * (1.f - tt);
    float alpha_t = tt * ALPHA_C + (1.f - tt) * (1.f - ALPHA_C);
    float om = 1.f - p_t;
    return alpha_t * om * om * ce;
}

// ---------------- prep: per-anchor int8 label table (-1 = negative) + zero acc ----------------
__global__ __launch_bounds__(256) void yolo_prep(
    const int* __restrict__ matched, const int* __restrict__ gt_labels,
    signed char* __restrict__ lblmap, double* __restrict__ acc)
{
    if (blockIdx.x == 0) acc[threadIdx.x] = 0.0;       // 256 = 4*NSLOT doubles
    const int qid = blockIdx.x * 256 + threadIdx.x;
    if (qid >= AN / 4) return;
    const int a0 = qid * 4;
    const int b  = a0 / NA;
    const int4 m4 = *(const int4*)(matched + a0);
    const int mm[4] = {m4.x, m4.y, m4.z, m4.w};
    char4 o;
    o.x = (mm[0] >= 0) ? (signed char)gt_labels[b * MAX_GT + mm[0]] : (signed char)-1;
    o.y = (mm[1] >= 0) ? (signed char)gt_labels[b * MAX_GT + mm[1]] : (signed char)-1;
    o.z = (mm[2] >= 0) ? (signed char)gt_labels[b * MAX_GT + mm[2]] : (signed char)-1;
    o.w = (mm[3] >= 0) ? (signed char)gt_labels[b * MAX_GT + mm[3]] : (signed char)-1;
    *(char4*)(lblmap + a0) = o;
}

// ---------------- mega: 1024-thread blocks; DFL+IoU blocks first, then cls ----------------
__global__ __launch_bounds__(1024, 4) void yolo_mega(
    const float* __restrict__ p0, const float* __restrict__ p1, const float* __restrict__ p2,
    const float* __restrict__ gt_bboxes, const int* __restrict__ matched,
    const signed char* __restrict__ lblmap, double* __restrict__ acc)
{
    const int bid  = blockIdx.x;
    const int slot = bid & (NSLOT - 1);

    if (bid < NB_DFL) {
        // ---- DFL + IoU: thread = (anchor, side k), k wave-uniform in high bits ----
        __shared__ float spd[4][1024];                 // [k][local anchor] (only [..][0..255] used)
        const int la = threadIdx.x & 255;              // local anchor
        const int k  = threadIdx.x >> 8;               // side, wave-uniform
        const int ga = bid * 256 + la;                 // global anchor, 0..268799 exact
        const int b  = ga / NA;
        const int ai = ga - b * NA;

        const float* p; int HW, off; float stride; int h, w;
        if (ai < 6400)      { p = p0; HW = 6400; off = ai;        stride = 8.f;
                              h = off / 80; w = off - h * 80; }
        else if (ai < 8000) { p = p1; HW = 1600; off = ai - 6400; stride = 16.f;
                              h = off / 40; w = off - h * 40; }
        else                { p = p2; HW = 400;  off = ai - 8000; stride = 32.f;
                              h = off / 20; w = off - h * 20; }
        const float cx = ((float)w + 0.5f) * stride;
        const float cy = ((float)h + 0.5f) * stride;

        const int m = matched[(size_t)b * NA + ai];
        const bool pos = (m >= 0);
        const int idx = pos ? m : 0;
        const float4 tb = *(const float4*)(gt_bboxes + ((size_t)b * MAX_GT + idx) * 4);

        float d = (k == 0) ? (cx - tb.x) : (k == 1) ? (cy - tb.y)
                : (k == 2) ? (tb.z - cx) : (tb.w - cy);
        float tval = fminf(fmaxf(d, 0.f) / stride, (float)(BINS - 1) - 1e-6f);
        const int   lo = (int)floorf(tval);            // 0..14 -> lo+1 valid
        const float fr = tval - (float)lo;

        // 16 bin logits, all loads issued up front (scalar, 256B/wave contiguous)
        const float* pc = p + (size_t)(b * 144 + k * BINS) * HW + off;
        float v[BINS];
        #pragma unroll
        for (int i = 0; i < BINS; ++i) v[i] = pc[(size_t)i * HW];

        float mx = v[0];
        #pragma unroll
        for (int i = 1; i < BINS; ++i) mx = fmaxf(mx, v[i]);
        float se = 0.f, we = 0.f, vlo = 0.f, vhi = 0.f;
        #pragma unroll
        for (int i = 0; i < BINS; ++i) {
            float e = __expf(v[i] - mx);
            se += e;
            we += (float)i * e;
            vlo = (i == lo)     ? v[i] : vlo;
            vhi = (i == lo + 1) ? v[i] : vhi;
        }

        float part = 0.f;
        if (pos) {
            float lse = mx + __logf(se);
            part = -((1.f - fr) * (vlo - lse) + fr * (vhi - lse));
        }
        spd[k][la] = (we / se) * stride;               // stride-4B write: conflict-free
        __syncthreads();

        float iou_part = 0.f, cnt = 0.f;
        if (k == 0 && pos) {
            float px1 = cx - spd[0][la], py1 = cy - spd[1][la];
            float px2 = cx + spd[2][la], py2 = cy + spd[3][la];
            float ix1 = fmaxf(px1, tb.x), iy1 = fmaxf(py1, tb.y);
            float ix2 = fminf(px2, tb.z), iy2 = fminf(py2, tb.w);
            float inter  = fmaxf(ix2 - ix1, 0.f) * fmaxf(iy2 - iy1, 0.f);
            float area_p = fmaxf(px2 - px1, 0.f) * fmaxf(py2 - py1, 0.f);
            float area_t = fmaxf(tb.z - tb.x, 0.f) * fmaxf(tb.w - tb.y, 0.f);
            float iou = inter / (area_p + area_t - inter + EPS_F);
            iou_part = 1.f - iou;
            cnt = 1.f;
        }
        block_reduce_atomic_16(part,     &acc[2 * NSLOT + slot]);
        block_reduce_atomic_16(iou_part, &acc[1 * NSLOT + slot]);
        block_reduce_atomic_16(cnt,      &acc[3 * NSLOT + slot]);
    } else {
        // ---- cls: 2 blocks per (b,c) plane; thread = one quad (4 anchors) ----
        const int cbid  = bid - NB_DFL;                // 0..5119
        const int half  = cbid & 1;
        const int plane = cbid >> 1;
        const int b = plane / NCLS;
        const int c = plane - b * NCLS;
        const size_t cls_ch = (size_t)(b * 144 + 4 * BINS + c);
        const signed char* lb0 = lblmap + b * NA;

        float part = 0.f;
        for (int q = (int)threadIdx.x; q < 1050; q += 1024) {
            const int t = half * 1050 + q;             // quad in image
            const float* p; int HW, off, gbase;
            if (t < 1600)      { p = p0; HW = 6400; off = t * 4;          gbase = 0;    }
            else if (t < 2000) { p = p1; HW = 1600; off = (t - 1600) * 4; gbase = 6400; }
            else               { p = p2; HW = 400;  off = (t - 2000) * 4; gbase = 8000; }

            float4 s4 = *(const float4*)(p + cls_ch * HW + off);
            char4  l4 = *(const char4*)(lb0 + gbase + off);
            part += focal_elem(s4.x, (c == l4.x) ? 1.f : 0.f);
            part += focal_elem(s4.y, (c == l4.y) ? 1.f : 0.f);
            part += focal_elem(s4.z, (c == l4.z) ? 1.f : 0.f);
            part += focal_elem(s4.w, (c == l4.w) ? 1.f : 0.f);
        }
        block_reduce_atomic_16(part, &acc[0 * NSLOT + slot]);
    }
}

// ---------------- fallback: known-good fused kernel (round 1) ----------------
__global__ __launch_bounds__(256) void yolo_loss_fused(
    const float* __restrict__ p0, const float* __restrict__ p1, const float* __restrict__ p2,
    const float* __restrict__ gt_bboxes, const int* __restrict__ gt_labels,
    const int* __restrict__ matched, double* __restrict__ acc)
{
    const int a = blockIdx.x * blockDim.x + threadIdx.x;
    const int b = blockIdx.y;
    const int slot = blockIdx.x & (NSLOT - 1);
    float cls_acc = 0.f, iou_acc = 0.f, dfl_acc = 0.f, pos_cnt = 0.f;
    if (a < NA) {
        const float* p; int HW, W; float stride; int off;
        if (a < 6400)      { p = p0; HW = 6400; W = 80; stride = 8.f;  off = a; }
        else if (a < 8000) { p = p1; HW = 1600; W = 40; stride = 16.f; off = a - 6400; }
        else               { p = p2; HW = 400;  W = 20; stride = 32.f; off = a - 8000; }
        const int h = off / W, w = off - h * W;
        const float cx = ((float)w + 0.5f) * stride, cy = ((float)h + 0.5f) * stride;
        const float* pb = p + ((size_t)b * 144) * (size_t)HW + (size_t)off;
        const int m = matched[(size_t)b * NA + a];
        const bool pos = (m >= 0);
        const int idx = pos ? m : 0;
        const int lbl = gt_labels[b * MAX_GT + idx];
        const float* tbp = gt_bboxes + ((size_t)b * MAX_GT + idx) * 4;
        const float tx1 = tbp[0], ty1 = tbp[1], tx2 = tbp[2], ty2 = tbp[3];
        float tdist[4] = {fmaxf(cx - tx1, 0.f) / stride, fmaxf(cy - ty1, 0.f) / stride,
                          fmaxf(tx2 - cx, 0.f) / stride, fmaxf(ty2 - cy, 0.f) / stride};
        float pdv[4]; float dfl_sum = 0.f;
        #pragma unroll
        for (int k = 0; k < 4; ++k) {
            float tv = fminf(tdist[k], (float)(BINS - 1) - 1e-6f);
            int lo = (int)floorf(tv);
            float fr = tv - (float)lo;
            const float* pc = pb + (size_t)(k * BINS) * HW;
            float v[BINS];
            #pragma unroll
            for (int i = 0; i < BINS; ++i) v[i] = pc[(size_t)i * HW];
            float mx = v[0];
            #pragma unroll
            for (int i = 1; i < BINS; ++i) mx = fmaxf(mx, v[i]);
            float se = 0.f, we = 0.f, vlo = 0.f, vhi = 0.f;
            #pragma unroll
            for (int i = 0; i < BINS; ++i) {
                float e = __expf(v[i] - mx);
                se += e; we += (float)i * e;
                vlo = (i == lo) ? v[i] : vlo;
                vhi = (i == lo + 1) ? v[i] : vhi;
            }
            pdv[k] = (we / se) * stride;
            if (pos) { float lse = mx + __logf(se); dfl_sum += -((1.f - fr) * (vlo - lse) + fr * (vhi - lse)); }
        }
        const float* pcls = pb + (size_t)(4 * BINS) * HW;
        #pragma unroll 4
        for (int c = 0; c < NCLS; ++c)
            cls_acc += focal_elem(pcls[(size_t)c * HW], (pos && c == lbl) ? 1.f : 0.f);
        if (pos) {
            float px1 = cx - pdv[0], py1 = cy - pdv[1], px2 = cx + pdv[2], py2 = cy + pdv[3];
            float ix1 = fmaxf(px1, tx1), iy1 = fmaxf(py1, ty1);
            float ix2 = fminf(px2, tx2), iy2 = fminf(py2, ty2);
            float inter  = fmaxf(ix2 - ix1, 0.f) * fmaxf(iy2 - iy1, 0.f);
            float area_p = fmaxf(px2 - px1, 0.f) * fmaxf(py2 - py1, 0.f);
            float area_t = fmaxf(tx2 - tx1, 0.f) * fmaxf(ty2 - ty1, 0.f);
            float iou = inter / (area_p + area_t - inter + EPS_F);
            iou_acc = 1.f - iou; dfl_acc = dfl_sum; pos_cnt = 1.f;
        }
    }
    block_reduce_atomic_4(cls_acc, &acc[0 * NSLOT + slot]);
    block_reduce_atomic_4(iou_acc, &acc[1 * NSLOT + slot]);
    block_reduce_atomic_4(dfl_acc, &acc[2 * NSLOT + slot]);
    block_reduce_atomic_4(pos_cnt, &acc[3 * NSLOT + slot]);
}

__global__ void yolo_loss_finalize(const double* __restrict__ acc, float* __restrict__ out)
{
    double s[4] = {0.0, 0.0, 0.0, 0.0};
    for (int q = 0; q < 4; ++q)
        for (int i = 0; i < NSLOT; ++i) s[q] += acc[q * NSLOT + i];
    double np = s[3] < 1.0 ? 1.0 : s[3];
    double total = W_CLS * s[0] / np + W_IOU * s[1] / np + W_DFL * s[2] / (np * 4.0);
    out[0] = (float)total;
}

extern "C" void kernel_launch(void* const* d_in, const int* in_sizes, int n_in,
                              void* d_out, int out_size, void* d_ws, size_t ws_size,
                              hipStream_t stream)
{
    const float* p0        = (const float*)d_in[0];
    const float* p1        = (const float*)d_in[1];
    const float* p2        = (const float*)d_in[2];
    const float* gt_bboxes = (const float*)d_in[3];
    const int*   gt_labels = (const int*)d_in[4];
    const int*   matched   = (const int*)d_in[5];
    float*  out = (float*)d_out;

    const size_t accBytes = 4 * NSLOT * sizeof(double);                 // 2048
    double*      acc    = (double*)d_ws;
    signed char* lblmap = (signed char*)((char*)d_ws + accBytes);
    const size_t need = accBytes + (size_t)AN;                          // ~271 KB

    if (ws_size >= need) {
        yolo_prep<<<(AN / 4 + 255) / 256, 256, 0, stream>>>(matched, gt_labels, lblmap, acc);
        yolo_mega<<<NB_DFL + NB_CLS, 1024, 0, stream>>>(p0, p1, p2, gt_bboxes, matched,
                                                        lblmap, acc);
    } else {
        (void)hipMemsetAsync(acc, 0, accBytes, stream);
        dim3 g((NA + 255) / 256, BATCH);
        yolo_loss_fused<<<g, 256, 0, stream>>>(p0, p1, p2, gt_bboxes, gt_labels, matched, acc);
    }
    yolo_loss_finalize<<<1, 1, 0, stream>>>(acc, out);
}